// Round 8
// baseline (257.149 us; speedup 1.0000x reference)
//
#include <hip/hip_runtime.h>

#define NNODES 100000
#define NEDGES 1600000
#define DFEAT  128
#define NPOOL  25000

#define SCAN_CHUNK 1024                              // elements per scan block
#define SCAN_BLOCKS ((NNODES + SCAN_CHUNK - 1) / SCAN_CHUNK)   // 98

#define NRANGE 8                                     // dst-range groups (== XCDs)
#define RSPAN ((NNODES + NRANGE - 1) / NRANGE)       // 12500 nodes per range
#define GCAP 210000                                  // per-group bucket capacity (E=200k, >20 sigma)

#define BBLOCKS 2048
#define GSTRIDE_B ((BBLOCKS / NRANGE) * 256)         // threads per range group in phase B

// bf16 RNE helpers (manual, deterministic)
__device__ __forceinline__ unsigned int f2bf(float f) {
    unsigned int b = __float_as_uint(f);
    return (b + 0x7fffu + ((b >> 16) & 1u)) >> 16;
}
__device__ __forceinline__ float bf2f_lo(unsigned int packed) {
    return __uint_as_float(packed << 16);
}
__device__ __forceinline__ float bf2f_hi(unsigned int packed) {
    return __uint_as_float(packed & 0xffff0000u);
}

// ---------------- convert x (f32) -> xh (bf16) ----------------
__global__ __launch_bounds__(256) void convert_kernel(const float* __restrict__ x,
                                                      unsigned int* __restrict__ xh_u32) {
    int i = blockIdx.x * blockDim.x + threadIdx.x;   // over (NNODES*DFEAT)/8
    const int n8 = NNODES * DFEAT / 8;
    if (i >= n8) return;
    float4 a = ((const float4*)x)[i * 2 + 0];
    float4 b = ((const float4*)x)[i * 2 + 1];
    uint4 o;
    o.x = f2bf(a.x) | (f2bf(a.y) << 16);
    o.y = f2bf(a.z) | (f2bf(a.w) << 16);
    o.z = f2bf(b.x) | (f2bf(b.y) << 16);
    o.w = f2bf(b.z) | (f2bf(b.w) << 16);
    ((uint4*)xh_u32)[i] = o;
}

// ---------------- CSR build, phase P: fused histogram + XCD-group partition ----
// Each block: one contiguous tile of 1024 edges. Coalesced int4/float4 loads,
// rowptr histogram atomics, LDS per-group counting (atomic old-value = slot),
// one global atomic per group per block to reserve a contiguous bucket run.
__global__ __launch_bounds__(256) void part_kernel(const int* __restrict__ dst,
                                                   const int* __restrict__ src,
                                                   const float* __restrict__ w,
                                                   int* __restrict__ rowptr,
                                                   int* __restrict__ gcur,
                                                   int2* __restrict__ bkt_sw,
                                                   int* __restrict__ bkt_dst) {
    __shared__ int lhist[NRANGE];
    __shared__ int lbase[NRANGE];
    const int n4 = NEDGES / 4;
    int i = blockIdx.x * blockDim.x + threadIdx.x;
    bool active = (i < n4);
    int4 d4 = make_int4(0, 0, 0, 0);
    int4 s4 = make_int4(0, 0, 0, 0);
    float4 w4 = make_float4(0.f, 0.f, 0.f, 0.f);
    if (active) {
        d4 = ((const int4*)dst)[i];
        s4 = ((const int4*)src)[i];
        w4 = ((const float4*)w)[i];
    }
    if (threadIdx.x < NRANGE) lhist[threadIdx.x] = 0;
    __syncthreads();
    int dv[4] = {d4.x, d4.y, d4.z, d4.w};
    int sv[4] = {s4.x, s4.y, s4.z, s4.w};
    float wv[4] = {w4.x, w4.y, w4.z, w4.w};
    int g[4], slot[4];
    if (active) {
        #pragma unroll
        for (int k = 0; k < 4; ++k) {
            atomicAdd(&rowptr[dv[k]], 1);            // fused histogram
            g[k] = dv[k] / RSPAN;
            slot[k] = atomicAdd(&lhist[g[k]], 1);    // old value = local slot
        }
    }
    __syncthreads();
    if (threadIdx.x < NRANGE)
        lbase[threadIdx.x] = atomicAdd(&gcur[threadIdx.x], lhist[threadIdx.x]);
    __syncthreads();
    if (active) {
        #pragma unroll
        for (int k = 0; k < 4; ++k) {
            int idx = g[k] * GCAP + lbase[g[k]] + slot[k];
            bkt_sw[idx] = make_int2(sv[k], __float_as_int(wv[k]));
            bkt_dst[idx] = dv[k];
        }
    }
}

// ---------------- scan (hierarchical, in-place on rowptr) ----------------

__global__ __launch_bounds__(256) void scan1_kernel(const int* __restrict__ rowptr,
                                                    int* __restrict__ partials) {
    __shared__ int lds[256];
    int t = threadIdx.x;
    int base = blockIdx.x * SCAN_CHUNK + t * 4;
    int sum = 0;
    #pragma unroll
    for (int k = 0; k < 4; ++k) {
        int i = base + k;
        if (i < NNODES) sum += rowptr[i];
    }
    lds[t] = sum;
    __syncthreads();
    for (int off = 128; off > 0; off >>= 1) {
        if (t < off) lds[t] += lds[t + off];
        __syncthreads();
    }
    if (t == 0) partials[blockIdx.x] = lds[0];
}

__global__ void scan2_kernel(int* __restrict__ partials) {
    __shared__ int lds[128];
    int t = threadIdx.x;
    int v = (t < SCAN_BLOCKS) ? partials[t] : 0;
    lds[t] = v;
    __syncthreads();
    for (int off = 1; off < 128; off <<= 1) {
        int u = (t >= off) ? lds[t - off] : 0;
        __syncthreads();
        lds[t] += u;
        __syncthreads();
    }
    if (t < SCAN_BLOCKS) partials[t] = lds[t] - v;   // exclusive
}

__global__ __launch_bounds__(256) void scan3_kernel(int* __restrict__ rowptr,
                                                    const int* __restrict__ partials) {
    __shared__ int lds[256];
    int t = threadIdx.x;
    int base = blockIdx.x * SCAN_CHUNK + t * 4;
    int v[4];
    int sum = 0;
    #pragma unroll
    for (int k = 0; k < 4; ++k) {
        int i = base + k;
        v[k] = (i < NNODES) ? rowptr[i] : 0;
        sum += v[k];
    }
    lds[t] = sum;
    __syncthreads();
    for (int off = 1; off < 256; off <<= 1) {
        int u = (t >= off) ? lds[t - off] : 0;
        __syncthreads();
        lds[t] += u;
        __syncthreads();
    }
    int run = partials[blockIdx.x] + lds[t] - sum;
    #pragma unroll
    for (int k = 0; k < 4; ++k) {
        int i = base + k;
        if (i < NNODES) rowptr[i] = run;
        run += v[k];
    }
}

// ---------------- CSR build, phase B: per-XCD local scatter ----------------
// Blocks bid%8==g drain bucket g (coalesced reads); scattered stores confined
// to csr_sw's 1.6 MB group slice -> stays L2-merged on that XCD.
// rowptr[t] becomes END pointer of row t.
__global__ __launch_bounds__(256) void scatter_kernel(const int2* __restrict__ bkt_sw,
                                                      const int* __restrict__ bkt_dst,
                                                      const int* __restrict__ gcur,
                                                      int* __restrict__ rowptr,
                                                      int2* __restrict__ csr_sw) {
    int g   = blockIdx.x & (NRANGE - 1);
    int sub = blockIdx.x >> 3;
    int n = gcur[g];
    const int2* bsw = bkt_sw + (size_t)g * GCAP;
    const int*  bd  = bkt_dst + (size_t)g * GCAP;
    for (int j = sub * 256 + threadIdx.x; j < n; j += GSTRIDE_B) {
        int2 sw = bsw[j];
        int t = bd[j];
        int pos = atomicAdd(&rowptr[t], 1);
        csr_sw[pos] = sw;
    }
}

// ---------------- aggregation ----------------
// After build: row t spans [ t ? rowptr[t-1] : 0 , rowptr[t] ).

__device__ __forceinline__ void agg_row_bf16(const unsigned int* __restrict__ xh,
                                             const int2* __restrict__ csr_sw,
                                             int beg, int end, int lane,
                                             float2& acc) {
    for (int base = beg; base < end; base += 64) {
        int cnt = end - base; if (cnt > 64) cnt = 64;
        int2 sw = make_int2(0, 0);
        if (lane < cnt) sw = csr_sw[base + lane];
        int   my_s = sw.x;
        float my_w = __int_as_float(sw.y);
        int d = 0;
        for (; d + 8 <= cnt; d += 8) {
            int s[8]; float wv[8]; unsigned int v[8];
            #pragma unroll
            for (int k = 0; k < 8; ++k) {
                s[k]  = __shfl(my_s, d + k);
                wv[k] = __shfl(my_w, d + k);
            }
            #pragma unroll
            for (int k = 0; k < 8; ++k) v[k] = xh[(size_t)s[k] * 64 + lane];
            #pragma unroll
            for (int k = 0; k < 8; ++k) {
                acc.x += bf2f_lo(v[k]) * wv[k];
                acc.y += bf2f_hi(v[k]) * wv[k];
            }
        }
        for (; d + 4 <= cnt; d += 4) {
            int s[4]; float wv[4]; unsigned int v[4];
            #pragma unroll
            for (int k = 0; k < 4; ++k) {
                s[k]  = __shfl(my_s, d + k);
                wv[k] = __shfl(my_w, d + k);
            }
            #pragma unroll
            for (int k = 0; k < 4; ++k) v[k] = xh[(size_t)s[k] * 64 + lane];
            #pragma unroll
            for (int k = 0; k < 4; ++k) {
                acc.x += bf2f_lo(v[k]) * wv[k];
                acc.y += bf2f_hi(v[k]) * wv[k];
            }
        }
        for (; d < cnt; ++d) {
            int   s = __shfl(my_s, d);
            float wv = __shfl(my_w, d);
            unsigned int v = xh[(size_t)s * 64 + lane];
            acc.x += bf2f_lo(v) * wv;
            acc.y += bf2f_hi(v) * wv;
        }
    }
}

// hop 1: x1h[n] = bf16( xh[n] + sum_e xh[src_e] * w_e )
__global__ __launch_bounds__(256) void agg1_kernel(const unsigned int* __restrict__ xh,
                                                   const int2* __restrict__ csr_sw,
                                                   const int* __restrict__ rowptr,
                                                   unsigned int* __restrict__ x1h) {
    int gid = blockIdx.x * blockDim.x + threadIdx.x;
    int node = gid >> 6;
    if (node >= NNODES) return;
    int lane = threadIdx.x & 63;
    int beg = node ? rowptr[node - 1] : 0;
    int end = rowptr[node];
    unsigned int r = xh[(size_t)node * 64 + lane];   // residual
    float2 acc = make_float2(bf2f_lo(r), bf2f_hi(r));
    agg_row_bf16(xh, csr_sw, beg, end, lane, acc);
    x1h[(size_t)node * 64 + lane] = f2bf(acc.x) | (f2bf(acc.y) << 16);
}

// hop 2: out[row] = x1h[sel] + sum_e x1h[src_e] * w_e   (f32 output)
__global__ __launch_bounds__(256) void agg2_kernel(const unsigned int* __restrict__ x1h,
                                                   const int2* __restrict__ csr_sw,
                                                   const int* __restrict__ rowptr,
                                                   const int* __restrict__ sel,
                                                   float* __restrict__ out) {
    int gid = blockIdx.x * blockDim.x + threadIdx.x;
    int row = gid >> 6;
    if (row >= NPOOL) return;
    int lane = threadIdx.x & 63;
    int node = sel[row];
    int beg = node ? rowptr[node - 1] : 0;
    int end = rowptr[node];
    unsigned int r = x1h[(size_t)node * 64 + lane];  // residual
    float2 acc = make_float2(bf2f_lo(r), bf2f_hi(r));
    agg_row_bf16(x1h, csr_sw, beg, end, lane, acc);
    ((float2*)out)[(size_t)row * 64 + lane] = acc;
}

// ---------------- launch ----------------

extern "C" void kernel_launch(void* const* d_in, const int* in_sizes, int n_in,
                              void* d_out, int out_size, void* d_ws, size_t ws_size,
                              hipStream_t stream) {
    const float* x         = (const float*)d_in[0];            // [NNODES, DFEAT]
    const float* edge_attr = (const float*)d_in[1];            // [NEDGES]
    const int*   edge_idx  = (const int*)d_in[2];              // [2, NEDGES]
    const int*   sel       = (const int*)d_in[3];              // [NPOOL]
    const int*   src = edge_idx;
    const int*   dst = edge_idx + NEDGES;
    float* out = (float*)d_out;

    // workspace layout: 25.6 + 25.6 + 0.4 + 12.8 + tiny = 64.4 MB (proven budget)
    char* ws = (char*)d_ws;
    unsigned int* xh  = (unsigned int*)ws;  ws += (size_t)NNODES * 64 * sizeof(unsigned int); // 25.6 MB
    char* scratch = ws;                     ws += (size_t)NNODES * 64 * sizeof(unsigned int); // 25.6 MB (x1h)
    int*   rowptr   = (int*)ws;    ws += (size_t)NNODES * sizeof(int);            // 0.4 MB
    int2*  csr_sw   = (int2*)ws;   ws += (size_t)NEDGES * sizeof(int2);           // 12.8 MB
    int*   partials = (int*)ws;    ws += (size_t)SCAN_BLOCKS * sizeof(int);
    int*   gcur     = (int*)ws;    ws += (size_t)NRANGE * sizeof(int);

    // bucket scratch aliases x1h (buckets dead before agg1 writes x1h)
    unsigned int* x1h = (unsigned int*)scratch;
    int2* bkt_sw  = (int2*)scratch;                                  // 8*210k*8B = 13.44 MB
    int*  bkt_dst = (int*)(scratch + (size_t)NRANGE * GCAP * sizeof(int2)); // 6.72 MB

    hipMemsetAsync(rowptr, 0, (size_t)NNODES * sizeof(int), stream);
    hipMemsetAsync(gcur, 0, (size_t)NRANGE * sizeof(int), stream);

    // 0) x -> bf16
    convert_kernel<<<(NNODES * DFEAT / 8 + 255) / 256, 256, 0, stream>>>(x, xh);
    // 1) phase P: fused histogram + partition into per-XCD buckets
    part_kernel<<<(NEDGES / 4 + 255) / 256, 256, 0, stream>>>(dst, src, edge_attr,
                                                              rowptr, gcur, bkt_sw, bkt_dst);
    // 2) hierarchical exclusive scan (in-place on rowptr)
    scan1_kernel<<<SCAN_BLOCKS, 256, 0, stream>>>(rowptr, partials);
    scan2_kernel<<<1, 128, 0, stream>>>(partials);
    scan3_kernel<<<SCAN_BLOCKS, 256, 0, stream>>>(rowptr, partials);
    // 3) phase B: per-XCD local scatter; rowptr becomes end-pointers
    scatter_kernel<<<BBLOCKS, 256, 0, stream>>>(bkt_sw, bkt_dst, gcur, rowptr, csr_sw);

    // 4) hop 1 (all nodes), bf16 gather, bf16 store
    {
        long long threads = (long long)NNODES * 64;
        int blocks = (int)((threads + 255) / 256);
        agg1_kernel<<<blocks, 256, 0, stream>>>(xh, csr_sw, rowptr, x1h);
    }
    // 5) hop 2 (selected rows only), bf16 gather, f32 out
    {
        long long threads = (long long)NPOOL * 64;
        int blocks = (int)((threads + 255) / 256);
        agg2_kernel<<<blocks, 256, 0, stream>>>(x1h, csr_sw, rowptr, sel, out);
    }
}